// Round 1
// baseline (2792.009 us; speedup 1.0000x reference)
//
#include <hip/hip_runtime.h>

#define HWX 4096   // 64*64 pixels per (b, channel) plane

// ---------------- conv 1x1 over virtual concat [inA(256ch), inB(256ch)] ----------------
// Each thread owns one pixel and TCO output channels. Weights are block-uniform -> s_load.
template<int TCO, bool RELU>
__global__ __launch_bounds__(256) void conv1x1_k(
    const float* __restrict__ inA, const float* __restrict__ inB,
    const float* __restrict__ w, const float* __restrict__ bias,
    float* __restrict__ out, int Cout)
{
  const int pix = blockIdx.x * 256 + threadIdx.x;   // 0..32767
  const int b = pix >> 12, pp = pix & 4095;
  const int co0 = blockIdx.y * TCO;

  float acc[TCO];
#pragma unroll
  for (int i = 0; i < TCO; ++i) acc[i] = 0.f;

  const float* pa = inA + ((size_t)b * 256) * HWX + pp;
  const float* pb = inB + ((size_t)b * 256) * HWX + pp;

  for (int ci = 0; ci < 256; ci += 4) {
    const float x0 = pa[(size_t)(ci + 0) * HWX];
    const float x1 = pa[(size_t)(ci + 1) * HWX];
    const float x2 = pa[(size_t)(ci + 2) * HWX];
    const float x3 = pa[(size_t)(ci + 3) * HWX];
#pragma unroll
    for (int co = 0; co < TCO; ++co) {
      const float* wp = w + (size_t)(co0 + co) * 512 + ci;
      float s = acc[co];
      s = fmaf(x0, wp[0], s);
      s = fmaf(x1, wp[1], s);
      s = fmaf(x2, wp[2], s);
      s = fmaf(x3, wp[3], s);
      acc[co] = s;
    }
  }
  for (int ci = 0; ci < 256; ci += 4) {
    const float x0 = pb[(size_t)(ci + 0) * HWX];
    const float x1 = pb[(size_t)(ci + 1) * HWX];
    const float x2 = pb[(size_t)(ci + 2) * HWX];
    const float x3 = pb[(size_t)(ci + 3) * HWX];
#pragma unroll
    for (int co = 0; co < TCO; ++co) {
      const float* wp = w + (size_t)(co0 + co) * 512 + 256 + ci;
      float s = acc[co];
      s = fmaf(x0, wp[0], s);
      s = fmaf(x1, wp[1], s);
      s = fmaf(x2, wp[2], s);
      s = fmaf(x3, wp[3], s);
      acc[co] = s;
    }
  }

#pragma unroll
  for (int co = 0; co < TCO; ++co) {
    float v = acc[co] + bias[co0 + co];
    if (RELU) v = fmaxf(v, 0.f);
    out[((size_t)b * Cout + (co0 + co)) * HWX + pp] = v;
  }
}

// ---------------- generic 3x3 conv, pad=1, NCHW, H=W=64 ----------------
// Block = 4 rows x 64 cols of one batch plane; stages 8 input channels (6x66 halo tile) in LDS.
template<int TCO, bool RELU>
__global__ __launch_bounds__(256) void conv3x3_k(
    const float* __restrict__ in, const float* __restrict__ w,
    const float* __restrict__ bias, float* __restrict__ out,
    int Cin, int Cout)
{
  __shared__ float tile[8][6][66];   // 12.7 KB
  const int b = blockIdx.z;
  const int y0 = blockIdx.x * 4;
  const int co0 = blockIdx.y * TCO;
  const int r = threadIdx.x >> 6;    // 0..3
  const int c = threadIdx.x & 63;    // 0..63

  float acc[TCO];
#pragma unroll
  for (int i = 0; i < TCO; ++i) acc[i] = 0.f;

  for (int ci0 = 0; ci0 < Cin; ci0 += 8) {
    __syncthreads();
    for (int e = threadIdx.x; e < 8 * 6 * 66; e += 256) {
      const int cc = e / 396;
      const int rem = e - cc * 396;
      const int rr = rem / 66;
      const int xx = rem - rr * 66;
      const int gy = y0 + rr - 1;
      const int gx = xx - 1;
      float v = 0.f;
      if (gy >= 0 && gy < 64 && gx >= 0 && gx < 64)
        v = in[(((size_t)b * Cin + ci0 + cc) << 12) + (gy << 6) + gx];
      tile[cc][rr][xx] = v;
    }
    __syncthreads();
    for (int cc = 0; cc < 8; ++cc) {
      const float x00 = tile[cc][r + 0][c + 0], x01 = tile[cc][r + 0][c + 1], x02 = tile[cc][r + 0][c + 2];
      const float x10 = tile[cc][r + 1][c + 0], x11 = tile[cc][r + 1][c + 1], x12 = tile[cc][r + 1][c + 2];
      const float x20 = tile[cc][r + 2][c + 0], x21 = tile[cc][r + 2][c + 1], x22 = tile[cc][r + 2][c + 2];
#pragma unroll
      for (int co = 0; co < TCO; ++co) {
        const float* wp = w + ((size_t)(co0 + co) * Cin + (ci0 + cc)) * 9;
        float s = acc[co];
        s = fmaf(x00, wp[0], s); s = fmaf(x01, wp[1], s); s = fmaf(x02, wp[2], s);
        s = fmaf(x10, wp[3], s); s = fmaf(x11, wp[4], s); s = fmaf(x12, wp[5], s);
        s = fmaf(x20, wp[6], s); s = fmaf(x21, wp[7], s); s = fmaf(x22, wp[8], s);
        acc[co] = s;
      }
    }
  }

#pragma unroll
  for (int co = 0; co < TCO; ++co) {
    if (co0 + co < Cout) {
      float v = acc[co] + bias[co0 + co];
      if (RELU) v = fmaxf(v, 0.f);
      out[(((size_t)b * Cout + (co0 + co)) << 12) + ((y0 + r) << 6) + c] = v;
    }
  }
}

// ---------------- assemble: out[b,c,y,x] = sum_{dy,dx} atten[b,dy*9+dx,y,x]*fh[b,c,y+dy-4,x+dx-4] ----------------
// Block = (b, y). Threads: 16 x-quads (float4 of x) x 16 channel slots; each thread does 16 channels.
__global__ __launch_bounds__(256) void assemble_k(
    const float* __restrict__ atten, const float* __restrict__ fh,
    float* __restrict__ out)
{
  __shared__ float att[81][64];      // 20.7 KB
  const int b = blockIdx.y, y = blockIdx.x;
  for (int e = threadIdx.x; e < 81 * 64; e += 256) {
    const int i = e >> 6, x = e & 63;
    att[i][x] = atten[(((size_t)b * 81 + i) << 12) + (y << 6) + x];
  }
  __syncthreads();

  const int quad = threadIdx.x & 15, x0 = quad << 2;
  const int csub = threadIdx.x >> 4;

  float acc[16][4];
#pragma unroll
  for (int i = 0; i < 16; ++i) {
    acc[i][0] = 0.f; acc[i][1] = 0.f; acc[i][2] = 0.f; acc[i][3] = 0.f;
  }

#pragma unroll
  for (int dy = 0; dy < 9; ++dy) {
    const int gy = y + dy - 4;
    if (gy < 0 || gy >= 64) continue;   // block-uniform branch
    // hoist attention quads for this dy (reused across all 16 channels)
    float av[9][4];
#pragma unroll
    for (int dx = 0; dx < 9; ++dx) {
      const float4 q = *reinterpret_cast<const float4*>(&att[dy * 9 + dx][x0]);
      av[dx][0] = q.x; av[dx][1] = q.y; av[dx][2] = q.z; av[dx][3] = q.w;
    }
#pragma unroll
    for (int cb = 0; cb < 16; ++cb) {
      const int ch = cb * 16 + csub;
      const float* row = fh + (((size_t)b * 256 + ch) << 12) + (gy << 6);
      float rv[12];   // cols x0-4 .. x0+7, sliding window over dx
#pragma unroll
      for (int k = 0; k < 3; ++k) {
        const int col0 = x0 - 4 + (k << 2);
        if (col0 >= 0 && col0 + 3 < 64) {
          const float4 q = *reinterpret_cast<const float4*>(row + col0);
          rv[4 * k + 0] = q.x; rv[4 * k + 1] = q.y; rv[4 * k + 2] = q.z; rv[4 * k + 3] = q.w;
        } else {
#pragma unroll
          for (int jj = 0; jj < 4; ++jj) {
            const int cl = col0 + jj;
            rv[4 * k + jj] = (cl >= 0 && cl < 64) ? row[cl] : 0.f;
          }
        }
      }
#pragma unroll
      for (int dx = 0; dx < 9; ++dx)
#pragma unroll
        for (int j = 0; j < 4; ++j)
          acc[cb][j] = fmaf(av[dx][j], rv[dx + j], acc[cb][j]);
    }
  }

#pragma unroll
  for (int cb = 0; cb < 16; ++cb) {
    const int ch = cb * 16 + csub;
    float4 q;
    q.x = acc[cb][0]; q.y = acc[cb][1]; q.z = acc[cb][2]; q.w = acc[cb][3];
    *reinterpret_cast<float4*>(out + (((size_t)b * 256 + ch) << 12) + (y << 6) + x0) = q;
  }
}

// ---------------- final tiny conv (3->2) + softmax over the 2 channels ----------------
__global__ __launch_bounds__(256) void logits_softmax_k(
    const float* __restrict__ g3, const float* __restrict__ fw4,
    const float* __restrict__ fb4, float* __restrict__ score)
{
  const int pix = blockIdx.x * 256 + threadIdx.x;  // 0..32767
  const int b = pix >> 12, pp = pix & 4095;
  const int y = pp >> 6, x = pp & 63;
  float l0 = fb4[0], l1 = fb4[1];
#pragma unroll
  for (int ci = 0; ci < 3; ++ci) {
    const float* g = g3 + (((size_t)b * 3 + ci) << 12);
#pragma unroll
    for (int dy = 0; dy < 3; ++dy) {
      const int gy = y + dy - 1;
      if (gy < 0 || gy >= 64) continue;
#pragma unroll
      for (int dx = 0; dx < 3; ++dx) {
        const int gx = x + dx - 1;
        if (gx < 0 || gx >= 64) continue;
        const float v = g[(gy << 6) + gx];
        l0 = fmaf(v, fw4[(0 * 3 + ci) * 9 + dy * 3 + dx], l0);
        l1 = fmaf(v, fw4[(1 * 3 + ci) * 9 + dy * 3 + dx], l1);
      }
    }
  }
  const float m = fmaxf(l0, l1);
  const float e0 = __expf(l0 - m), e1 = __expf(l1 - m);
  const float inv = 1.f / (e0 + e1);
  score[((size_t)b * 2 + 0) * HWX + pp] = e0 * inv;
  score[((size_t)b * 2 + 1) * HWX + pp] = e1 * inv;
}

// ---------------- out = s0*f + s1*aligned ----------------
__global__ __launch_bounds__(256) void blend_k(
    const float* __restrict__ score, const float* __restrict__ f,
    const float* __restrict__ alg, float* __restrict__ out)
{
  const size_t q = (size_t)blockIdx.x * 256 + threadIdx.x;  // 0..2097151
  const size_t e = q << 2;
  const int b = (int)(e >> 20);                // 256*4096 floats per batch
  const int rem = (int)(e & 1048575);
  const int pp = rem & 4095;
  const float4 s0 = *reinterpret_cast<const float4*>(score + ((size_t)b * 2 + 0) * HWX + pp);
  const float4 s1 = *reinterpret_cast<const float4*>(score + ((size_t)b * 2 + 1) * HWX + pp);
  const float4 fv = *reinterpret_cast<const float4*>(f + e);
  const float4 av = *reinterpret_cast<const float4*>(alg + e);
  float4 o;
  o.x = s0.x * fv.x + s1.x * av.x;
  o.y = s0.y * fv.y + s1.y * av.y;
  o.z = s0.z * fv.z + s1.z * av.z;
  o.w = s0.w * fv.w + s1.w * av.w;
  *reinterpret_cast<float4*>(out + e) = o;
}

extern "C" void kernel_launch(void* const* d_in, const int* in_sizes, int n_in,
                              void* d_out, int out_size, void* d_ws, size_t ws_size,
                              hipStream_t stream) {
  const float* f   = (const float*)d_in[0];
  const float* fh  = (const float*)d_in[1];
  const float* aw1 = (const float*)d_in[2];
  const float* ab1 = (const float*)d_in[3];
  const float* aw2 = (const float*)d_in[4];
  const float* ab2 = (const float*)d_in[5];
  const float* aw3 = (const float*)d_in[6];
  const float* ab3 = (const float*)d_in[7];
  const float* fw1 = (const float*)d_in[8];
  const float* fb1 = (const float*)d_in[9];
  const float* fw2 = (const float*)d_in[10];
  const float* fb2 = (const float*)d_in[11];
  const float* fw3 = (const float*)d_in[12];
  const float* fb3 = (const float*)d_in[13];
  const float* fw4 = (const float*)d_in[14];
  const float* fb4 = (const float*)d_in[15];
  float* out = (float*)d_out;

  float* ws = (float*)d_ws;
  float* a1     = ws;                 // [8,256,64,64]  (also g1)
  float* a2     = a1 + 8388608;       // [8,128,64,64]  (also g2 [8,16,..])
  float* att    = a2 + 4194304;       // [8,81,64,64]
  float* alg    = att + 2654208;      // [8,256,64,64]
  float* g3b    = alg + 8388608;      // [8,3,64,64]
  float* scoreb = g3b + 98304;        // [8,2,64,64]

  dim3 blk(256);
  // atten path
  conv1x1_k<64, true ><<<dim3(128, 4, 1), blk, 0, stream>>>(f, fh, aw1, ab1, a1, 256);
  conv3x3_k<32, true ><<<dim3(16, 4, 8),  blk, 0, stream>>>(a1, aw2, ab2, a2, 256, 128);
  conv3x3_k<27, false><<<dim3(16, 3, 8),  blk, 0, stream>>>(a2, aw3, ab3, att, 128, 81);
  // assemble
  assemble_k<<<dim3(64, 8), blk, 0, stream>>>(att, fh, alg);
  // final path
  conv1x1_k<64, true ><<<dim3(128, 4, 1), blk, 0, stream>>>(f, alg, fw1, fb1, a1, 256);
  conv3x3_k<16, true ><<<dim3(16, 1, 8),  blk, 0, stream>>>(a1, fw2, fb2, a2, 256, 16);
  conv3x3_k< 3, false><<<dim3(16, 1, 8),  blk, 0, stream>>>(a2, fw3, fb3, g3b, 16, 3);
  logits_softmax_k<<<dim3(128), blk, 0, stream>>>(g3b, fw4, fb4, scoreb);
  blend_k<<<dim3(8192), blk, 0, stream>>>(scoreb, f, alg, out);
}

// Round 3
// 748.311 us; speedup vs baseline: 3.7311x; 3.7311x over previous
//
#include <hip/hip_runtime.h>

#define HWX 4096   // 64*64 pixels per (b, channel) plane

typedef __bf16 bf8 __attribute__((ext_vector_type(8)));
typedef float f4 __attribute__((ext_vector_type(4)));

// ---------------- weight pack: fp32 [Cout][Cin][taps] -> bf16 hi/lo [CoutPad][taps][Cin] ----------------
__global__ __launch_bounds__(256) void packw_k(
    const float* __restrict__ w, __bf16* __restrict__ whi, __bf16* __restrict__ wlo,
    int Cout, int CoutPad, int Cin, int taps)
{
  const int idx = blockIdx.x * 256 + threadIdx.x;
  const int tot = CoutPad * taps * Cin;
  if (idx >= tot) return;
  const int co = idx / (taps * Cin);
  const int rem = idx - co * taps * Cin;
  const int tap = rem / Cin;
  const int ci = rem - tap * Cin;
  const float v = (co < Cout) ? w[((size_t)co * Cin + ci) * taps + tap] : 0.f;
  const __bf16 h = (__bf16)v;
  whi[idx] = h;
  wlo[idx] = (__bf16)(v - (float)h);
}

// ---------------- MFMA implicit-GEMM conv (1x1 or 3x3 pad=1), NCHW, H=W=64 ----------------
// C[cout][pix] = sum_k W[cout][k] * X[k][pix].  Block = 256 thr = 4 waves.
// NCOW waves split couts (16 each); 4/NCOW waves split rows. Each wave: 16 couts x 64 px (one image row).
// Split-bf16: x=xh+xl, w=wh+wl; acc += wh*xh + wh*xl + wl*xh  (~fp32 precision).
template<int NCOW, int TAPS, bool RELU, bool CONCAT>
__global__ __launch_bounds__(256) void convmm_k(
    const float* __restrict__ inA, const float* __restrict__ inB,
    const __bf16* __restrict__ whi, const __bf16* __restrict__ wlo,
    const float* __restrict__ bias,
    float* __restrict__ out, int CinA, int CinTot, int Cout)
{
  const int lane = threadIdx.x & 63;
  const int wv = threadIdx.x >> 6;
  const int wco = wv % NCOW;
  const int yg = wv / NCOW;
  constexpr int ROWS = 4 / NCOW;
  const int pb = blockIdx.x * ROWS + yg;         // global image row 0..511
  const int b = pb >> 6, y = pb & 63;
  const int co0 = blockIdx.y * (16 * NCOW) + wco * 16;
  const int colb = lane & 15;                    // px col within 16-tile (also A's co row sel)
  const int g = lane >> 4;                       // k lane-group

  f4 acc[4] = {f4{0,0,0,0}, f4{0,0,0,0}, f4{0,0,0,0}, f4{0,0,0,0}};
  const size_t wbase = (size_t)(co0 + colb) * TAPS * CinTot;

  for (int tap = 0; tap < TAPS; ++tap) {
    int dxm1 = 0, gy = y;
    if (TAPS == 9) {
      const int dy = tap / 3;
      dxm1 = tap - dy * 3 - 1;
      gy = y + dy - 1;
      if ((unsigned)gy >= 64u) continue;         // zero-pad row: whole tap contributes 0
    }
    const int rowoff = gy << 6;
    for (int ci0 = 0; ci0 < CinTot; ci0 += 32) {
      // A fragments: 8 consecutive bf16 weights (16B aligned) for this lane's cout
      const size_t wo = wbase + (size_t)tap * CinTot + ci0 + g * 8;
      const bf8 ah = *reinterpret_cast<const bf8*>(whi + wo);
      const bf8 al = *reinterpret_cast<const bf8*>(wlo + wo);
      // B source plane base (uniform per K-step; concat boundary is 32-aligned)
      const int cibase = ci0 + g * 8;
      const float* src;
      if (CONCAT) {
        src = (cibase < CinA) ? inA + (((size_t)b * CinA + cibase) << 12)
                              : inB + (((size_t)b * CinA + (cibase - CinA)) << 12);
      } else {
        src = inA + (((size_t)b * CinTot + cibase) << 12);
      }
      src += rowoff;
#pragma unroll
      for (int fr = 0; fr < 4; ++fr) {
        const int xe = fr * 16 + colb + dxm1;
        const bool ok = (TAPS == 1) || ((unsigned)xe < 64u);   // zero-pad column
        const float* sp = src + xe;
        bf8 bh, bl;
#pragma unroll
        for (int j = 0; j < 8; ++j) {
          const float v = ok ? sp[(size_t)j << 12] : 0.f;      // per-lane predicated load
          const __bf16 h = (__bf16)v;
          bh[j] = h;
          bl[j] = (__bf16)(v - (float)h);
        }
        acc[fr] = __builtin_amdgcn_mfma_f32_16x16x32_bf16(ah, bh, acc[fr], 0, 0, 0);
        acc[fr] = __builtin_amdgcn_mfma_f32_16x16x32_bf16(ah, bl, acc[fr], 0, 0, 0);
        acc[fr] = __builtin_amdgcn_mfma_f32_16x16x32_bf16(al, bh, acc[fr], 0, 0, 0);
      }
    }
  }

  // Epilogue: D row=(lane>>4)*4+reg -> cout, col=lane&15 -> px. 16-lane groups store 64B spans.
  const size_t ob = ((size_t)b * Cout) << 12;
#pragma unroll
  for (int r = 0; r < 4; ++r) {
    const int co = co0 + g * 4 + r;
    if (co < Cout) {
      const float bv = bias[co];
#pragma unroll
      for (int fr = 0; fr < 4; ++fr) {
        float v = acc[fr][r] + bv;
        if (RELU) v = fmaxf(v, 0.f);
        out[ob + ((size_t)co << 12) + (y << 6) + fr * 16 + colb] = v;
      }
    }
  }
}

// ---------------- generic fp32 3x3 conv (kept only for tiny 16->3) ----------------
template<int TCO, bool RELU>
__global__ __launch_bounds__(256) void conv3x3_k(
    const float* __restrict__ in, const float* __restrict__ w,
    const float* __restrict__ bias, float* __restrict__ out,
    int Cin, int Cout)
{
  __shared__ float tile[8][6][66];
  const int b = blockIdx.z;
  const int y0 = blockIdx.x * 4;
  const int co0 = blockIdx.y * TCO;
  const int r = threadIdx.x >> 6;
  const int c = threadIdx.x & 63;

  float acc[TCO];
#pragma unroll
  for (int i = 0; i < TCO; ++i) acc[i] = 0.f;

  for (int ci0 = 0; ci0 < Cin; ci0 += 8) {
    __syncthreads();
    for (int e = threadIdx.x; e < 8 * 6 * 66; e += 256) {
      const int cc = e / 396;
      const int rem = e - cc * 396;
      const int rr = rem / 66;
      const int xx = rem - rr * 66;
      const int gy = y0 + rr - 1;
      const int gx = xx - 1;
      float v = 0.f;
      if (gy >= 0 && gy < 64 && gx >= 0 && gx < 64)
        v = in[(((size_t)b * Cin + ci0 + cc) << 12) + (gy << 6) + gx];
      tile[cc][rr][xx] = v;
    }
    __syncthreads();
    for (int cc = 0; cc < 8; ++cc) {
      const float x00 = tile[cc][r + 0][c + 0], x01 = tile[cc][r + 0][c + 1], x02 = tile[cc][r + 0][c + 2];
      const float x10 = tile[cc][r + 1][c + 0], x11 = tile[cc][r + 1][c + 1], x12 = tile[cc][r + 1][c + 2];
      const float x20 = tile[cc][r + 2][c + 0], x21 = tile[cc][r + 2][c + 1], x22 = tile[cc][r + 2][c + 2];
#pragma unroll
      for (int co = 0; co < TCO; ++co) {
        const float* wp = w + ((size_t)(co0 + co) * Cin + (ci0 + cc)) * 9;
        float s = acc[co];
        s = fmaf(x00, wp[0], s); s = fmaf(x01, wp[1], s); s = fmaf(x02, wp[2], s);
        s = fmaf(x10, wp[3], s); s = fmaf(x11, wp[4], s); s = fmaf(x12, wp[5], s);
        s = fmaf(x20, wp[6], s); s = fmaf(x21, wp[7], s); s = fmaf(x22, wp[8], s);
        acc[co] = s;
      }
    }
  }

#pragma unroll
  for (int co = 0; co < TCO; ++co) {
    if (co0 + co < Cout) {
      float v = acc[co] + bias[co0 + co];
      if (RELU) v = fmaxf(v, 0.f);
      out[(((size_t)b * Cout + (co0 + co)) << 12) + ((y0 + r) << 6) + c] = v;
    }
  }
}

// ---------------- assemble: out[b,c,y,x] = sum_{dy,dx} atten[b,dy*9+dx,y,x]*fh_pad[b,c,y+dy-4,x+dx-4] ----------------
__global__ __launch_bounds__(256) void assemble_k(
    const float* __restrict__ atten, const float* __restrict__ fh,
    float* __restrict__ out)
{
  __shared__ float att[81][64];
  const int b = blockIdx.y, y = blockIdx.x;
  for (int e = threadIdx.x; e < 81 * 64; e += 256) {
    const int i = e >> 6, x = e & 63;
    att[i][x] = atten[(((size_t)b * 81 + i) << 12) + (y << 6) + x];
  }
  __syncthreads();

  const int quad = threadIdx.x & 15, x0 = quad << 2;
  const int csub = threadIdx.x >> 4;

  float acc[16][4];
#pragma unroll
  for (int i = 0; i < 16; ++i) {
    acc[i][0] = 0.f; acc[i][1] = 0.f; acc[i][2] = 0.f; acc[i][3] = 0.f;
  }

#pragma unroll
  for (int dy = 0; dy < 9; ++dy) {
    const int gy = y + dy - 4;
    if (gy < 0 || gy >= 64) continue;
    float av[9][4];
#pragma unroll
    for (int dx = 0; dx < 9; ++dx) {
      const float4 q = *reinterpret_cast<const float4*>(&att[dy * 9 + dx][x0]);
      av[dx][0] = q.x; av[dx][1] = q.y; av[dx][2] = q.z; av[dx][3] = q.w;
    }
#pragma unroll
    for (int cb = 0; cb < 16; ++cb) {
      const int ch = cb * 16 + csub;
      const float* row = fh + (((size_t)b * 256 + ch) << 12) + (gy << 6);
      float rv[12];
#pragma unroll
      for (int k = 0; k < 3; ++k) {
        const int col0 = x0 - 4 + (k << 2);
        if (col0 >= 0 && col0 + 3 < 64) {
          const float4 q = *reinterpret_cast<const float4*>(row + col0);
          rv[4 * k + 0] = q.x; rv[4 * k + 1] = q.y; rv[4 * k + 2] = q.z; rv[4 * k + 3] = q.w;
        } else {
#pragma unroll
          for (int jj = 0; jj < 4; ++jj) {
            const int cl = col0 + jj;
            rv[4 * k + jj] = (cl >= 0 && cl < 64) ? row[cl] : 0.f;
          }
        }
      }
#pragma unroll
      for (int dx = 0; dx < 9; ++dx)
#pragma unroll
        for (int j = 0; j < 4; ++j)
          acc[cb][j] = fmaf(av[dx][j], rv[dx + j], acc[cb][j]);
    }
  }

#pragma unroll
  for (int cb = 0; cb < 16; ++cb) {
    const int ch = cb * 16 + csub;
    float4 q;
    q.x = acc[cb][0]; q.y = acc[cb][1]; q.z = acc[cb][2]; q.w = acc[cb][3];
    *reinterpret_cast<float4*>(out + (((size_t)b * 256 + ch) << 12) + (y << 6) + x0) = q;
  }
}

// ---------------- final tiny conv (3->2) + softmax over the 2 channels ----------------
__global__ __launch_bounds__(256) void logits_softmax_k(
    const float* __restrict__ g3, const float* __restrict__ fw4,
    const float* __restrict__ fb4, float* __restrict__ score)
{
  const int pix = blockIdx.x * 256 + threadIdx.x;
  const int b = pix >> 12, pp = pix & 4095;
  const int y = pp >> 6, x = pp & 63;
  float l0 = fb4[0], l1 = fb4[1];
#pragma unroll
  for (int ci = 0; ci < 3; ++ci) {
    const float* g = g3 + (((size_t)b * 3 + ci) << 12);
#pragma unroll
    for (int dy = 0; dy < 3; ++dy) {
      const int gy = y + dy - 1;
      if (gy < 0 || gy >= 64) continue;
#pragma unroll
      for (int dx = 0; dx < 3; ++dx) {
        const int gx = x + dx - 1;
        if (gx < 0 || gx >= 64) continue;
        const float v = g[(gy << 6) + gx];
        l0 = fmaf(v, fw4[(0 * 3 + ci) * 9 + dy * 3 + dx], l0);
        l1 = fmaf(v, fw4[(1 * 3 + ci) * 9 + dy * 3 + dx], l1);
      }
    }
  }
  const float m = fmaxf(l0, l1);
  const float e0 = __expf(l0 - m), e1 = __expf(l1 - m);
  const float inv = 1.f / (e0 + e1);
  score[((size_t)b * 2 + 0) * HWX + pp] = e0 * inv;
  score[((size_t)b * 2 + 1) * HWX + pp] = e1 * inv;
}

// ---------------- out = s0*f + s1*aligned ----------------
__global__ __launch_bounds__(256) void blend_k(
    const float* __restrict__ score, const float* __restrict__ f,
    const float* __restrict__ alg, float* __restrict__ out)
{
  const size_t q = (size_t)blockIdx.x * 256 + threadIdx.x;
  const size_t e = q << 2;
  const int b = (int)(e >> 20);
  const int rem = (int)(e & 1048575);
  const int pp = rem & 4095;
  const float4 s0 = *reinterpret_cast<const float4*>(score + ((size_t)b * 2 + 0) * HWX + pp);
  const float4 s1 = *reinterpret_cast<const float4*>(score + ((size_t)b * 2 + 1) * HWX + pp);
  const float4 fv = *reinterpret_cast<const float4*>(f + e);
  const float4 av = *reinterpret_cast<const float4*>(alg + e);
  float4 o;
  o.x = s0.x * fv.x + s1.x * av.x;
  o.y = s0.y * fv.y + s1.y * av.y;
  o.z = s0.z * fv.z + s1.z * av.z;
  o.w = s0.w * fv.w + s1.w * av.w;
  *reinterpret_cast<float4*>(out + e) = o;
}

extern "C" void kernel_launch(void* const* d_in, const int* in_sizes, int n_in,
                              void* d_out, int out_size, void* d_ws, size_t ws_size,
                              hipStream_t stream) {
  const float* f   = (const float*)d_in[0];
  const float* fh  = (const float*)d_in[1];
  const float* aw1 = (const float*)d_in[2];
  const float* ab1 = (const float*)d_in[3];
  const float* aw2 = (const float*)d_in[4];
  const float* ab2 = (const float*)d_in[5];
  const float* aw3 = (const float*)d_in[6];
  const float* ab3 = (const float*)d_in[7];
  const float* fw1 = (const float*)d_in[8];
  const float* fb1 = (const float*)d_in[9];
  const float* fw2 = (const float*)d_in[10];
  const float* fb2 = (const float*)d_in[11];
  const float* fw3 = (const float*)d_in[12];
  const float* fb3 = (const float*)d_in[13];
  const float* fw4 = (const float*)d_in[14];
  const float* fb4 = (const float*)d_in[15];
  float* out = (float*)d_out;

  float* ws = (float*)d_ws;
  float* a1     = ws;                 // [8,256,64,64]  (also g1)
  float* a2     = a1 + 8388608;       // [8,128,64,64]  (also g2 [8,16,..])
  float* att    = a2 + 4194304;       // [8,81,64,64]
  float* alg    = att + 2654208;      // [8,256,64,64]
  float* g3b    = alg + 8388608;      // [8,3,64,64]
  float* scoreb = g3b + 98304;        // [8,2,64,64]
  __bf16* wpkb  = (__bf16*)(scoreb + 65536);
  __bf16* w1h   = wpkb;               // 256*512
  __bf16* w1l   = w1h + 131072;
  __bf16* w2h   = w1l + 131072;       // 128*9*256
  __bf16* w2l   = w2h + 294912;
  __bf16* w3h   = w2l + 294912;       // 96*9*128 (padded couts)
  __bf16* w3l   = w3h + 110592;
  __bf16* fw1h  = w3l + 110592;       // 256*512
  __bf16* fw1l  = fw1h + 131072;
  __bf16* fw2h  = fw1l + 131072;      // 16*9*256
  __bf16* fw2l  = fw2h + 36864;

  dim3 blk(256);
  // weight packing (data-independent, every call)
  packw_k<<<dim3(512),  blk, 0, stream>>>(aw1, w1h, w1l, 256, 256, 512, 1);
  packw_k<<<dim3(1152), blk, 0, stream>>>(aw2, w2h, w2l, 128, 128, 256, 9);
  packw_k<<<dim3(432),  blk, 0, stream>>>(aw3, w3h, w3l, 81, 96, 128, 9);
  packw_k<<<dim3(512),  blk, 0, stream>>>(fw1, fw1h, fw1l, 256, 256, 512, 1);
  packw_k<<<dim3(144),  blk, 0, stream>>>(fw2, fw2h, fw2l, 16, 16, 256, 9);

  // atten path
  convmm_k<4, 1, true,  true ><<<dim3(512, 4), blk, 0, stream>>>(f, fh, w1h, w1l, ab1, a1, 256, 512, 256);
  convmm_k<4, 9, true,  false><<<dim3(512, 2), blk, 0, stream>>>(a1, nullptr, w2h, w2l, ab2, a2, 0, 256, 128);
  convmm_k<2, 9, false, false><<<dim3(256, 3), blk, 0, stream>>>(a2, nullptr, w3h, w3l, ab3, att, 0, 128, 81);
  // assemble (fp32)
  assemble_k<<<dim3(64, 8), blk, 0, stream>>>(att, fh, alg);
  // final path
  convmm_k<4, 1, true,  true ><<<dim3(512, 4), blk, 0, stream>>>(f, alg, fw1h, fw1l, fb1, a1, 256, 512, 256);
  convmm_k<1, 9, true,  false><<<dim3(128, 1), blk, 0, stream>>>(a1, nullptr, fw2h, fw2l, fb2, a2, 0, 256, 16);
  conv3x3_k<3, false><<<dim3(16, 1, 8), blk, 0, stream>>>(a2, fw3, fb3, g3b, 16, 3);
  logits_softmax_k<<<dim3(128), blk, 0, stream>>>(g3b, fw4, fb4, scoreb);
  blend_k<<<dim3(8192), blk, 0, stream>>>(scoreb, f, alg, out);
}